// Round 4
// baseline (267.822 us; speedup 1.0000x reference)
//
#include <hip/hip_runtime.h>
#include <hip/hip_bf16.h>

#define NB   4
#define C    256
#define NPIX 4096
#define EPSV 1e-5f
#define K2   0.09016844f   // C^-0.5 * log2(e): softmax in exp2 domain
#define KVB  32
#define NSPLIT 4
#define NKVS (NPIX / NSPLIT)     // 1024 kv per block
#define NSTEPS (NKVS / KVB)      // 32 steps

typedef __bf16 bf16x8 __attribute__((ext_vector_type(8)));
typedef float  f32x4  __attribute__((ext_vector_type(4)));
typedef __hip_bfloat16 bf16;

// ---------------------------------------------------------------------------
// Kernel 1: transpose fp32 [C][N] -> bf16 [N][C], fused gate partial sums
// ---------------------------------------------------------------------------
__global__ __launch_bounds__(256) void k_transpose(
    const float* __restrict__ x1, const float* __restrict__ x2,
    const float* __restrict__ gate_w,
    bf16* __restrict__ xt1, bf16* __restrict__ xt2, float* __restrict__ gate_ws)
{
    __shared__ float tile[64][65];
    const int nt = blockIdx.x, ct = blockIdx.y, z = blockIdx.z;
    const int b = z >> 1, which = z & 1;
    const float* x = which ? x2 : x1;
    bf16* xt = which ? xt2 : xt1;
    const int t = threadIdx.x;
    const int n0 = nt * 64, c0 = ct * 64;

    const float* xp = x + ((size_t)b * C + c0) * NPIX + n0;
#pragma unroll
    for (int i = 0; i < 16; ++i) {
        int cl = (t >> 6) + i * 4, nl = t & 63;
        tile[cl][nl] = xp[(size_t)cl * NPIX + nl];
    }
    __syncthreads();

    {
        int nl = t & 63, q = t >> 6;
        float s = 0.f;
#pragma unroll
        for (int i = 0; i < 16; ++i) {
            int cl = q * 16 + i;
            s += tile[cl][nl] * gate_w[which * C + c0 + cl];
        }
        atomicAdd(&gate_ws[b * NPIX + n0 + nl], s);
    }

    bf16* xtp = xt + ((size_t)b * NPIX + n0) * C + c0;
#pragma unroll
    for (int i = 0; i < 16; ++i) {
        int nl = (t >> 6) + i * 4, cl = t & 63;
        xtp[(size_t)nl * C + cl] = __float2bfloat16(tile[cl][nl]);
    }
}

// ---------------------------------------------------------------------------
// Kernel 2: QKV projections via bf16 MFMA (unchanged)
// ---------------------------------------------------------------------------
__global__ __launch_bounds__(256) void k_qkv(
    const bf16* __restrict__ xt1, const bf16* __restrict__ xt2,
    const float* __restrict__ qw, const float* __restrict__ qb,
    const float* __restrict__ kw, const float* __restrict__ kb,
    const float* __restrict__ vw, const float* __restrict__ vb,
    bf16* __restrict__ Qt, bf16* __restrict__ Kt, bf16* __restrict__ Vv)
{
    const int nt = blockIdx.x, ot = blockIdx.y, zp = blockIdx.z;
    const int b = zp / 3, pidx = zp % 3;
    const bf16* xt = (pidx == 0) ? xt1 : xt2;
    const float* w    = (pidx == 0) ? qw : (pidx == 1) ? kw : vw;
    const float* bias = (pidx == 0) ? qb : (pidx == 1) ? kb : vb;

    const int wave = threadIdx.x >> 6, lane = threadIdx.x & 63;
    const int g = lane >> 4, l15 = lane & 15;
    const int n0 = nt * 64 + wave * 16;
    const int o0 = ot * 64;

    bf16x8 a[8];
    const bf16* xrow = xt + ((size_t)b * NPIX + n0 + l15) * C;
#pragma unroll
    for (int cb = 0; cb < 8; ++cb)
        a[cb] = *reinterpret_cast<const bf16x8*>(xrow + cb * 32 + 8 * g);

#pragma unroll
    for (int os = 0; os < 4; ++os) {
        const int oo = o0 + os * 16;
        const float* wrow = w + (size_t)(oo + l15) * C;
        f32x4 acc = {0.f, 0.f, 0.f, 0.f};
#pragma unroll
        for (int cb = 0; cb < 8; ++cb) {
            const float4* wp = reinterpret_cast<const float4*>(wrow + cb * 32 + 8 * g);
            float4 w0 = wp[0], w1 = wp[1];
            bf16x8 bfrag = { (__bf16)w0.x, (__bf16)w0.y, (__bf16)w0.z, (__bf16)w0.w,
                             (__bf16)w1.x, (__bf16)w1.y, (__bf16)w1.z, (__bf16)w1.w };
            if (pidx < 2)
                acc = __builtin_amdgcn_mfma_f32_16x16x32_bf16(a[cb], bfrag, acc, 0, 0, 0);
            else
                acc = __builtin_amdgcn_mfma_f32_16x16x32_bf16(bfrag, a[cb], acc, 0, 0, 0);
        }
        if (pidx < 2) {
            float bv = bias[oo + l15];
            bf16* dst = ((pidx == 0) ? Qt : Kt) + ((size_t)b * NPIX + n0 + 4 * g) * C + oo + l15;
#pragma unroll
            for (int r = 0; r < 4; ++r)
                dst[(size_t)r * C] = __float2bfloat16(acc[r] + bv);
        } else {
            bf16* dst = Vv + ((size_t)b * C + oo + 4 * g) * NPIX + n0 + l15;
#pragma unroll
            for (int r = 0; r < 4; ++r)
                dst[(size_t)r * NPIX] = __float2bfloat16(acc[r] + bias[oo + 4 * g + r]);
        }
    }
}

// ---------------------------------------------------------------------------
// Kernel 3: flash attention v4.
// Wave owns 32 q-rows (two 16-q tiles) -> each K/V LDS fragment read feeds
// 2 MFMAs (halves LDS pipe load per FLOP). Block = 4 waves = 128 q.
// KV-split x4 -> 512 blocks (2/CU). KVB=32, LDS 74KB double-buffered.
// V swizzle fixed to (c>>1)&3 (2-way banks instead of 4-way).
// ---------------------------------------------------------------------------
#define SMEM_ATTN 75776   // K 2x16K @0, V 2x16K @32768, P 4x2560 @65536
#define SZP ((size_t)NPIX * C)

__device__ __forceinline__ void gload16(const void* g, void* l) {
    __builtin_amdgcn_global_load_lds(
        (const __attribute__((address_space(1))) void*)g,
        (__attribute__((address_space(3))) void*)l, 16, 0, 0);
}

__global__ __launch_bounds__(256, 2) void k_attn(
    const bf16* __restrict__ Qt, const bf16* __restrict__ Kt,
    const bf16* __restrict__ Vv, bf16* __restrict__ O0,
    bf16* __restrict__ O1, float2* __restrict__ mlws)
{
    extern __shared__ __align__(16) char smem[];
    const int id = blockIdx.x;
    const int combo = id & 15, nt = id >> 4;    // XCD id%8 -> 2 fixed combos
    const int b = combo >> 2, split = combo & 3;
    const int m_base = split * NKVS;
    const int wave = threadIdx.x >> 6, lane = threadIdx.x & 63;
    const int g = lane >> 4, l15 = lane & 15;
    const int n0 = nt * 128 + wave * 32;

    char* Pl = smem + 65536 + wave * 2560;      // [32 rows][80B]
    const int k_mloc = lane >> 5, k_slot = lane & 31;
    const int v_cloc = lane >> 2, v_slot = lane & 3;
    const int vsw = (v_cloc >> 1) & 3;          // corrected V swizzle bits

    const bf16* Kg = Kt + (size_t)b * NPIX * C;   // [N][C]
    const bf16* Vg = Vv + (size_t)b * C * NPIX;   // [C][N]

    bf16x8 q[2][8];
#pragma unroll
    for (int h = 0; h < 2; ++h) {
        const bf16* qrow = Qt + ((size_t)b * NPIX + n0 + h * 16 + l15) * C;
#pragma unroll
        for (int cb = 0; cb < 8; ++cb)
            q[h][cb] = *reinterpret_cast<const bf16x8*>(qrow + cb * 32 + 8 * g);
    }

    f32x4 o[2][16];
#pragma unroll
    for (int h = 0; h < 2; ++h)
#pragma unroll
        for (int i = 0; i < 16; ++i) o[h][i] = {0.f, 0.f, 0.f, 0.f};
    float m_run[2] = {-3.0e38f, -3.0e38f}, l_run[2] = {0.f, 0.f};

    auto stage = [&](int buf, int m0) {
        char* kd = smem + buf * 16384;            // K: [32 rows][512B]
#pragma unroll
        for (int ii = 0; ii < 4; ++ii) {
            const int i = wave * 4 + ii;
            const int m = 2 * i + k_mloc;
            gload16(Kg + ((size_t)(m0 + m)) * C + (k_slot ^ (m & 7)) * 8,
                    kd + i * 1024);
        }
        char* vd = smem + 32768 + buf * 16384;    // V: [256 rows][64B]
#pragma unroll
        for (int ii = 0; ii < 4; ++ii) {
            const int i = wave * 4 + ii;
            const int c = 16 * i + v_cloc;
            gload16(Vg + (size_t)c * NPIX + m0 + (v_slot ^ vsw) * 8,
                    vd + i * 1024);
        }
    };

    stage(0, m_base);
    asm volatile("s_waitcnt vmcnt(0)" ::: "memory");
    __syncthreads();

    const int swk = (l15 & 7) * 16;
    const int swv = 16 * (g ^ ((l15 >> 1) & 3));

    for (int t = 0; t < NSTEPS; ++t) {
        const int buf = t & 1;
        if (t + 1 < NSTEPS) stage(buf ^ 1, m_base + (t + 1) * KVB);

        const char* Kl = smem + buf * 16384;
        const char* Vl = smem + 32768 + buf * 16384;

        // ---- QK^T swapped: D[kv][q], shared K-frag feeds both q-halves ----
        f32x4 sa[2][2], sb[2][2];
#pragma unroll
        for (int h = 0; h < 2; ++h)
#pragma unroll
            for (int tt = 0; tt < 2; ++tt) { sa[h][tt] = {0,0,0,0}; sb[h][tt] = {0,0,0,0}; }
        __builtin_amdgcn_s_setprio(1);
#pragma unroll
        for (int tt = 0; tt < 2; ++tt) {
            const char* krow = Kl + (tt * 16 + l15) * 512;
#pragma unroll
            for (int cb = 0; cb < 4; ++cb) {
                bf16x8 kf = *reinterpret_cast<const bf16x8*>(krow + (((cb * 4 + g) * 16) ^ swk));
                sa[0][tt] = __builtin_amdgcn_mfma_f32_16x16x32_bf16(kf, q[0][cb], sa[0][tt], 0, 0, 0);
                sa[1][tt] = __builtin_amdgcn_mfma_f32_16x16x32_bf16(kf, q[1][cb], sa[1][tt], 0, 0, 0);
            }
#pragma unroll
            for (int cb = 4; cb < 8; ++cb) {
                bf16x8 kf = *reinterpret_cast<const bf16x8*>(krow + (((cb * 4 + g) * 16) ^ swk));
                sb[0][tt] = __builtin_amdgcn_mfma_f32_16x16x32_bf16(kf, q[0][cb], sb[0][tt], 0, 0, 0);
                sb[1][tt] = __builtin_amdgcn_mfma_f32_16x16x32_bf16(kf, q[1][cb], sb[1][tt], 0, 0, 0);
            }
        }
        __builtin_amdgcn_s_setprio(0);

        // ---- softmax per half: lane owns q=l15; kv = 16tt + 4g + r ----
        float v8[2][8], mx[2];
#pragma unroll
        for (int h = 0; h < 2; ++h) {
#pragma unroll
            for (int tt = 0; tt < 2; ++tt)
#pragma unroll
                for (int r = 0; r < 4; ++r)
                    v8[h][tt * 4 + r] = (sa[h][tt][r] + sb[h][tt][r]) * K2;
            float m = fmaxf(fmaxf(fmaxf(v8[h][0], v8[h][1]), fmaxf(v8[h][2], v8[h][3])),
                            fmaxf(fmaxf(v8[h][4], v8[h][5]), fmaxf(v8[h][6], v8[h][7])));
            m = fmaxf(m, __shfl_xor(m, 16));
            m = fmaxf(m, __shfl_xor(m, 32));
            mx[h] = m;
        }

        bool ok = (mx[0] <= m_run[0] + 8.f) & (mx[1] <= m_run[1] + 8.f);
        if (!__all(ok)) {
#pragma unroll
            for (int h = 0; h < 2; ++h) {
                float mnew = fmaxf(m_run[h], mx[h]);
                float cf = exp2f(m_run[h] - mnew);
                m_run[h] = mnew;
                l_run[h] *= cf;
                float cfq[4];
#pragma unroll
                for (int r = 0; r < 4; ++r) cfq[r] = __shfl(cf, 4 * g + r);
#pragma unroll
                for (int ct = 0; ct < 16; ++ct)
#pragma unroll
                    for (int r = 0; r < 4; ++r) o[h][ct][r] *= cfq[r];
            }
        }

#pragma unroll
        for (int h = 0; h < 2; ++h) {
            bf16 pr[8];
            float p[8];
#pragma unroll
            for (int j = 0; j < 8; ++j) {
                p[j] = exp2f(v8[h][j] - m_run[h]);
                pr[j] = __float2bfloat16(p[j]);
            }
            float sum = ((p[0] + p[1]) + (p[2] + p[3])) + ((p[4] + p[5]) + (p[6] + p[7]));
            sum += __shfl_xor(sum, 16);
            sum += __shfl_xor(sum, 32);
            l_run[h] += sum;

            char* prow = Pl + (h * 16 + l15) * 80;
            *reinterpret_cast<uint64_t*>(prow + 8 * g)      = *reinterpret_cast<uint64_t*>(&pr[0]);
            *reinterpret_cast<uint64_t*>(prow + 8 * g + 32) = *reinterpret_cast<uint64_t*>(&pr[4]);
        }

        // ---- PV: O[h] += P[h] * V, shared V-frag feeds both halves ----
        bf16x8 pf0 = *reinterpret_cast<const bf16x8*>(Pl + (l15) * 80 + 16 * g);
        bf16x8 pf1 = *reinterpret_cast<const bf16x8*>(Pl + (16 + l15) * 80 + 16 * g);
        __builtin_amdgcn_s_setprio(1);
#pragma unroll
        for (int ct = 0; ct < 16; ++ct) {
            const int c = ct * 16 + l15;
            bf16x8 vf = *reinterpret_cast<const bf16x8*>(Vl + c * 64 + swv);
            o[0][ct] = __builtin_amdgcn_mfma_f32_16x16x32_bf16(pf0, vf, o[0][ct], 0, 0, 0);
            o[1][ct] = __builtin_amdgcn_mfma_f32_16x16x32_bf16(pf1, vf, o[1][ct], 0, 0, 0);
        }
        __builtin_amdgcn_s_setprio(0);

        asm volatile("s_waitcnt vmcnt(0)" ::: "memory");
        __syncthreads();
    }

    // ---- epilogue: normalized partial + (m,l) ----
    const int pp = split * NB + b;
    bf16* base = (pp < 8) ? (O0 + (size_t)pp * SZP) : (O1 + (size_t)(pp - 8) * SZP);
#pragma unroll
    for (int h = 0; h < 2; ++h) {
        float invl = 1.0f / l_run[h];
        float invq[4];
#pragma unroll
        for (int r = 0; r < 4; ++r) invq[r] = __shfl(invl, 4 * g + r);
        bf16* dst = base + (size_t)(n0 + h * 16 + 4 * g) * C;
#pragma unroll
        for (int ct = 0; ct < 16; ++ct)
#pragma unroll
            for (int r = 0; r < 4; ++r)
                dst[(size_t)r * C + ct * 16 + l15] = __float2bfloat16(o[h][ct][r] * invq[r]);
    }
    if (lane < 16) {
#pragma unroll
        for (int h = 0; h < 2; ++h)
            mlws[(size_t)pp * NPIX + n0 + h * 16 + l15] = make_float2(m_run[h], l_run[h]);
    }
}

// ---------------------------------------------------------------------------
// Kernel 3b: combine the 4 KV splits -> Ot bf16 [B][N][C]
// ---------------------------------------------------------------------------
__global__ __launch_bounds__(256) void k_combine(
    const bf16* __restrict__ O0, const bf16* __restrict__ O1,
    const float2* __restrict__ ml, bf16* __restrict__ Ot)
{
    const int tid = blockIdx.x * 256 + threadIdx.x;  // 524288 threads
    const int c8 = tid & 31;
    const int rest = tid >> 5;
    const int n = rest & 4095;
    const int b = rest >> 12;

    float2 a[NSPLIT];
#pragma unroll
    for (int s = 0; s < NSPLIT; ++s)
        a[s] = ml[(size_t)(s * NB + b) * NPIX + n];
    float M = fmaxf(fmaxf(a[0].x, a[1].x), fmaxf(a[2].x, a[3].x));
    float w[NSPLIT], tot = 0.f;
#pragma unroll
    for (int s = 0; s < NSPLIT; ++s) { w[s] = exp2f(a[s].x - M) * a[s].y; tot += w[s]; }
    float rs = 1.0f / tot;
#pragma unroll
    for (int s = 0; s < NSPLIT; ++s) w[s] *= rs;

    const size_t off = (size_t)n * C + c8 * 8;
    float acc[8] = {0,0,0,0,0,0,0,0};
#pragma unroll
    for (int s = 0; s < NSPLIT; ++s) {
        const int pp = s * NB + b;
        const bf16* src = ((pp < 8) ? (O0 + (size_t)pp * SZP)
                                    : (O1 + (size_t)(pp - 8) * SZP)) + off;
        bf16x8 x = *reinterpret_cast<const bf16x8*>(src);
#pragma unroll
        for (int j = 0; j < 8; ++j) acc[j] += w[s] * (float)x[j];
    }
    bf16 outv[8];
#pragma unroll
    for (int j = 0; j < 8; ++j) outv[j] = __float2bfloat16(acc[j]);
    *reinterpret_cast<bf16x8*>(Ot + ((size_t)b * NPIX + n) * C + c8 * 8) =
        *reinterpret_cast<bf16x8*>(outv);
}

// ---------------------------------------------------------------------------
// Kernel 4: proj GEMM + BN + ReLU + gate + residual (unchanged)
// ---------------------------------------------------------------------------
__global__ __launch_bounds__(256) void k_proj(
    const bf16* __restrict__ Ot, const float* __restrict__ pw,
    const float* __restrict__ pb, const float* __restrict__ bn_g,
    const float* __restrict__ bn_b, const float* __restrict__ bn_m,
    const float* __restrict__ bn_v, const float* __restrict__ gate_ws,
    const float* __restrict__ gate_b, const float* __restrict__ x1,
    float* __restrict__ out)
{
    const int nt = blockIdx.x, otile = blockIdx.y, b = blockIdx.z;
    const int wave = threadIdx.x >> 6, lane = threadIdx.x & 63;
    const int g = lane >> 4, l15 = lane & 15;
    const int o0 = otile * 64 + wave * 16;

    bf16x8 a[8];
    const float* wrow = pw + (size_t)(o0 + l15) * C;
#pragma unroll
    for (int cb = 0; cb < 8; ++cb) {
        const float4* wp = reinterpret_cast<const float4*>(wrow + cb * 32 + 8 * g);
        float4 w0 = wp[0], w1 = wp[1];
        bf16x8 t = { (__bf16)w0.x, (__bf16)w0.y, (__bf16)w0.z, (__bf16)w0.w,
                     (__bf16)w1.x, (__bf16)w1.y, (__bf16)w1.z, (__bf16)w1.w };
        a[cb] = t;
    }
    const float gb = gate_b[0];

#pragma unroll
    for (int ns = 0; ns < 4; ++ns) {
        const int n0 = nt * 64 + ns * 16;
        f32x4 acc = {0.f, 0.f, 0.f, 0.f};
        const bf16* orow = Ot + ((size_t)b * NPIX + n0 + l15) * C;
#pragma unroll
        for (int cb = 0; cb < 8; ++cb) {
            bf16x8 bf = *reinterpret_cast<const bf16x8*>(orow + cb * 32 + 8 * g);
            acc = __builtin_amdgcn_mfma_f32_16x16x32_bf16(a[cb], bf, acc, 0, 0, 0);
        }
        float gsum = gate_ws[b * NPIX + n0 + l15];
        float gate = 1.f / (1.f + __expf(-(gsum + gb)));
#pragma unroll
        for (int r = 0; r < 4; ++r) {
            int oc = o0 + 4 * g + r;
            float scl = bn_g[oc] * rsqrtf(bn_v[oc] + EPSV);
            float v = (acc[r] + pb[oc] - bn_m[oc]) * scl + bn_b[oc];
            v = fmaxf(v, 0.f);
            size_t idx = ((size_t)b * C + oc) * NPIX + n0 + l15;
            out[idx] = x1[idx] + gate * v;
        }
    }
}

// ---------------------------------------------------------------------------
extern "C" void kernel_launch(void* const* d_in, const int* in_sizes, int n_in,
                              void* d_out, int out_size, void* d_ws, size_t ws_size,
                              hipStream_t stream)
{
    const float* x1  = (const float*)d_in[0];
    const float* x2  = (const float*)d_in[1];
    const float* q_w = (const float*)d_in[2];
    const float* q_b = (const float*)d_in[3];
    const float* k_w = (const float*)d_in[4];
    const float* k_b = (const float*)d_in[5];
    const float* v_w = (const float*)d_in[6];
    const float* v_b = (const float*)d_in[7];
    const float* p_w = (const float*)d_in[8];
    const float* p_b = (const float*)d_in[9];
    const float* bn_g = (const float*)d_in[10];
    const float* bn_b = (const float*)d_in[11];
    const float* bn_m = (const float*)d_in[12];
    const float* bn_v = (const float*)d_in[13];
    const float* g_w  = (const float*)d_in[14];
    const float* g_b  = (const float*)d_in[15];
    float* out = (float*)d_out;

    const size_t szBF = (size_t)NB * NPIX * C * sizeof(bf16);   // 8 MiB
    char* p = (char*)d_ws;
    bf16* xt1 = (bf16*)p; p += szBF;     // xt1+xt2: contiguous 16MB
    bf16* xt2 = (bf16*)p; p += szBF;
    bf16* Qt  = (bf16*)p; p += szBF;
    bf16* Kt  = (bf16*)p; p += szBF;
    bf16* Vv  = (bf16*)p; p += szBF;
    float* gate_ws = (float*)p; p += (size_t)NB * NPIX * sizeof(float);
    float2* mlws = (float2*)p;           // 16 x 4096 x 8B = 512KB

    // partial pools: pp 0..7 in d_out (16MB), pp 8..15 in xt1..xt2 (16MB)
    bf16* O0 = (bf16*)d_out;
    bf16* O1 = xt1;
    bf16* Ot = Qt;                       // Qt dead after k_attn

    hipFuncSetAttribute((const void*)k_attn,
                        hipFuncAttributeMaxDynamicSharedMemorySize, SMEM_ATTN);

    hipMemsetAsync(gate_ws, 0, (size_t)NB * NPIX * sizeof(float), stream);
    k_transpose<<<dim3(64, 4, 8),  256, 0, stream>>>(x1, x2, g_w, xt1, xt2, gate_ws);
    k_qkv     <<<dim3(64, 4, 12), 256, 0, stream>>>(xt1, xt2, q_w, q_b, k_w, k_b,
                                                    v_w, v_b, Qt, Kt, Vv);
    k_attn    <<<dim3(512), 256, SMEM_ATTN, stream>>>(Qt, Kt, Vv, O0, O1, mlws);
    k_combine <<<dim3(2048), 256, 0, stream>>>(O0, O1, mlws, Ot);
    k_proj    <<<dim3(64, 4, 4),  256, 0, stream>>>(Ot, p_w, p_b, bn_g, bn_b, bn_m,
                                                    bn_v, gate_ws, g_b, x1, out);
}